// Round 1
// baseline (152.975 us; speedup 1.0000x reference)
//
#include <hip/hip_runtime.h>
#include <math.h>
#include <float.h>

// VQ-VAE quantizer: x [16,1,128,2048] f32, emb [1024,128] f32
// out: quantized [16,128,2048] f32 (gathered codes), then loss scalar at [4194304]
//
// Kernel 1: per block = one (b, t0) tile of 128 points.
//   - stage x tile as xs[d][t] (coalesced: input is [B,D,T])
//   - loop 8 k-tiles of 128 codes: stage es[k][d], compute |e|^2, fp32
//     register-tiled GEMM (8x8 per thread), running argmin of |e|^2 - 2 x.e
//   - cross-thread argmin reduce (strict <, tie -> smaller k, matching np.argmin)
//   - epilogue: gather e[idx], write quantized, per-block loss partial
// Kernel 2: reduce 256 partials -> loss.

#define TD 128
#define TT 128
#define TK 128
#define NKT 8
#define ESP 132   // padded row (16B-aligned rows, odd-ish bank pattern)

__global__ __launch_bounds__(256, 1)
void vq_main(const float* __restrict__ x, const float* __restrict__ emb,
             float* __restrict__ out, float* __restrict__ partial) {
  __shared__ __align__(16) float xs[TD * TT];     // 64 KB  [d][t]
  __shared__ __align__(16) float es[TK * ESP];    // 67.6 KB [k][d+pad]
  __shared__ __align__(16) float cs[TK];          // |e_k|^2
  __shared__ __align__(16) float rv[16 * TT];     // per-ty argmin value
  __shared__ __align__(16) int   rk[16 * TT];     // per-ty argmin index
  __shared__ int   kfin[TT];
  __shared__ float wsum[4];

  const int tid = threadIdx.x;
  const int tx = tid & 15;
  const int ty = tid >> 4;
  const int tile = blockIdx.x;
  const int b = tile >> 4;
  const int t0 = (tile & 15) << 7;

  // ---- stage x tile: xs[d][t] ----
  const float* xp = x + (size_t)b * TD * 2048 + t0;
  for (int i = tid * 4; i < TD * TT; i += 1024) {
    int dd = i >> 7, tt = i & 127;
    *(float4*)&xs[dd * TT + tt] = *(const float4*)&xp[(size_t)dd * 2048 + tt];
  }

  float minv[8];
  int   mink[8];
#pragma unroll
  for (int i = 0; i < 8; ++i) { minv[i] = FLT_MAX; mink[i] = 0; }

  for (int kt = 0; kt < NKT; ++kt) {
    const int k0 = kt << 7;
    __syncthreads();  // protect es from previous iteration readers (and xs stage at kt=0)
    const float* ep = emb + (size_t)k0 * TD;
    for (int i = tid * 4; i < TK * TD; i += 1024) {
      int kk = i >> 7, dd = i & 127;
      *(float4*)&es[kk * ESP + dd] = *(const float4*)&ep[(size_t)kk * TD + dd];
    }
    __syncthreads();
    if (tid < TK) {
      const float* row = &es[tid * ESP];
      float s = 0.f;
#pragma unroll
      for (int dd = 0; dd < TD; dd += 4) {
        float4 v = *(const float4*)&row[dd];
        s = fmaf(v.x, v.x, s); s = fmaf(v.y, v.y, s);
        s = fmaf(v.z, v.z, s); s = fmaf(v.w, v.w, s);
      }
      cs[tid] = s;
    }
    __syncthreads();

    float acc[8][8];
#pragma unroll
    for (int i = 0; i < 8; ++i)
#pragma unroll
      for (int j = 0; j < 8; ++j) acc[i][j] = 0.f;

#pragma unroll 4
    for (int d = 0; d < TD; ++d) {
      float4 xa = *(const float4*)&xs[d * TT + tx * 4];
      float4 xb = *(const float4*)&xs[d * TT + 64 + tx * 4];
      float xv[8] = {xa.x, xa.y, xa.z, xa.w, xb.x, xb.y, xb.z, xb.w};
      float ev[8];
#pragma unroll
      for (int j = 0; j < 4; ++j) {
        ev[j]     = es[(ty * 4 + j) * ESP + d];
        ev[j + 4] = es[(64 + ty * 4 + j) * ESP + d];
      }
#pragma unroll
      for (int i = 0; i < 8; ++i)
#pragma unroll
        for (int j = 0; j < 8; ++j)
          acc[i][j] = fmaf(xv[i], ev[j], acc[i][j]);
    }

    // running argmin update; j ascending => k ascending within thread,
    // strict < keeps first occurrence
#pragma unroll
    for (int j = 0; j < 8; ++j) {
      int kl = (j < 4) ? (ty * 4 + j) : (64 + ty * 4 + (j - 4));
      float c = cs[kl];
      int kg = k0 + kl;
#pragma unroll
      for (int i = 0; i < 8; ++i) {
        float v = fmaf(-2.f, acc[i][j], c);
        if (v < minv[i]) { minv[i] = v; mink[i] = kg; }
      }
    }
  }

  // ---- cross-ty argmin reduce ----
#pragma unroll
  for (int i = 0; i < 8; ++i) {
    int tl = (i < 4) ? (tx * 4 + i) : (64 + tx * 4 + (i - 4));
    rv[ty * TT + tl] = minv[i];
    rk[ty * TT + tl] = mink[i];
  }
  __syncthreads();
  if (tid < TT) {
    float best = rv[tid];
    int bkk = rk[tid];
#pragma unroll
    for (int y = 1; y < 16; ++y) {
      float v = rv[y * TT + tid];
      int k = rk[y * TT + tid];
      if (v < best || (v == best && k < bkk)) { best = v; bkk = k; }
    }
    kfin[tid] = bkk;
  }
  __syncthreads();

  // ---- epilogue: gather, write quantized, loss partial ----
  float lsum = 0.f;
  float* op = out + (size_t)b * TD * 2048 + t0;
  for (int i = tid; i < TD * TT; i += 256) {
    int dd = i >> 7, tt = i & 127;
    float e = emb[(size_t)kfin[tt] * TD + dd];
    float xv = xs[dd * TT + tt];
    float df = e - xv;
    lsum = fmaf(df, df, lsum);
    op[(size_t)dd * 2048 + tt] = e;
  }
#pragma unroll
  for (int off = 32; off; off >>= 1) lsum += __shfl_down(lsum, off, 64);
  if ((tid & 63) == 0) wsum[tid >> 6] = lsum;
  __syncthreads();
  if (tid == 0) partial[blockIdx.x] = (wsum[0] + wsum[1]) + (wsum[2] + wsum[3]);
}

__global__ void vq_loss(const float* __restrict__ partial, float* __restrict__ out) {
  int lane = threadIdx.x;  // 64 threads
  float s = (partial[lane] + partial[lane + 64]) +
            (partial[lane + 128] + partial[lane + 192]);
#pragma unroll
  for (int off = 32; off; off >>= 1) s += __shfl_down(s, off, 64);
  if (lane == 0) out[4194304] = 1.25f * s / 4194304.0f;
}

extern "C" void kernel_launch(void* const* d_in, const int* in_sizes, int n_in,
                              void* d_out, int out_size, void* d_ws, size_t ws_size,
                              hipStream_t stream) {
  const float* x   = (const float*)d_in[0];   // [16,1,128,2048]
  const float* emb = (const float*)d_in[1];   // [1024,128]
  float* out = (float*)d_out;
  float* partial = (float*)d_ws;              // 256 floats
  vq_main<<<256, 256, 0, stream>>>(x, emb, out, partial);
  vq_loss<<<1, 64, 0, stream>>>(partial, out);
}

// Round 2
// 57.149 us; speedup vs baseline: 2.6768x; 2.6768x over previous
//
#include <hip/hip_runtime.h>
#include <math.h>
#include <float.h>

// VQ-VAE quantizer via bf16-split MFMA emulation of the fp32 distance GEMM.
// x [16,1,128,2048] f32, emb [1024,128] f32 -> quantized [16,128,2048] f32 + loss.
//
// score(t,k) = x_t . e_k - |e_k|^2/2   (argmax score == argmin d2)
// x,e split into bf16 hi+lo; 3 MFMA products (hh, hl, lh); -|e|^2/2 folded into
// the MFMA C-initializer. Top-2 per point tracked, then exact fp32 rescore of
// both candidates (replicates round-1's verified fp32 decision on near-ties).

typedef __attribute__((ext_vector_type(8))) short bf16x8;
typedef __attribute__((ext_vector_type(16))) float f32x16;

#define EBUF_HALF 65536   // one chunk: eh 32KB + el 32KB
#define EH2_OFF   131072  // 4KB: -0.5*|e|^2 for all 1024 codes
#define KFIN_OFF  135168  // 128 ints
#define WSUM_OFF  135680  // 4 floats
#define SMEM_BYTES 135696

__device__ __forceinline__ unsigned short f2bf(float f) {
  unsigned u = __float_as_uint(f);
  unsigned r = u + 0x7FFFu + ((u >> 16) & 1u);   // RNE
  return (unsigned short)(r >> 16);
}
__device__ __forceinline__ float bf2f(unsigned short h) {
  return __uint_as_float(((unsigned)h) << 16);
}

typedef __attribute__((address_space(1))) const void gas_t;
typedef __attribute__((address_space(3))) void las_t;
__device__ __forceinline__ void glds16(const void* g, void* l) {
  __builtin_amdgcn_global_load_lds((gas_t*)g, (las_t*)l, 16, 0, 0);
}

// ---- prep: emb f32 -> eh/el bf16 [1024][128] + eh2 = -0.5*|e|^2 (f32) ----
__global__ __launch_bounds__(256)
void vq_prep(const float* __restrict__ emb, unsigned short* __restrict__ ehg,
             unsigned short* __restrict__ elg, float* __restrict__ eh2g) {
  const int tid = threadIdx.x;
  const int r = blockIdx.x * 16 + (tid >> 4);
  const int seg = tid & 15;
  const float* row = emb + (size_t)r * 128 + seg * 8;
  float4 f0 = *(const float4*)&row[0];
  float4 f1 = *(const float4*)&row[4];
  float fv[8] = {f0.x, f0.y, f0.z, f0.w, f1.x, f1.y, f1.z, f1.w};
  bf16x8 H, L;
  float ssq = 0.f;
#pragma unroll
  for (int j = 0; j < 8; ++j) {
    float f = fv[j];
    ssq = fmaf(f, f, ssq);
    unsigned short h = f2bf(f);
    float res = f - bf2f(h);
    H[j] = (short)h;
    L[j] = (short)f2bf(res);
  }
  *(bf16x8*)(ehg + (size_t)r * 128 + seg * 8) = H;
  *(bf16x8*)(elg + (size_t)r * 128 + seg * 8) = L;
#pragma unroll
  for (int off = 1; off < 16; off <<= 1) ssq += __shfl_xor(ssq, off, 64);
  if (seg == 0) eh2g[r] = -0.5f * ssq;
}

// ---- main: 256 blocks x 256 thr; block = 128 points; wave = 32 points ----
__global__ __launch_bounds__(256, 1)
void vq_main(const float* __restrict__ x, const float* __restrict__ emb,
             const unsigned short* __restrict__ ehg,
             const unsigned short* __restrict__ elg,
             const float* __restrict__ eh2g,
             float* __restrict__ out, float* __restrict__ partial) {
  __shared__ __align__(16) char smem[SMEM_BYTES];
  float* eh2s = (float*)(smem + EH2_OFF);
  int* kfin = (int*)(smem + KFIN_OFF);
  float* wsum = (float*)(smem + WSUM_OFF);

  const int tid = threadIdx.x;
  const int lane = tid & 63;
  const int w = tid >> 6;
  const int hf = lane >> 5;        // which K-half of the mfma this lane feeds
  const int c32 = lane & 31;       // mfma column = point within wave
  const int blk = blockIdx.x;
  const int b = blk >> 4;
  const int tblk = (blk & 15) << 7;
  const int t = tblk + w * 32 + c32;
  const size_t bOff = (size_t)b * 262144;   // b*128*2048

  // stage chunk 0 (async, LDS linear dest + inverse-swizzled global src) + eh2
  {
    char* ldsA = smem + w * 8192;
    char* ldsB = smem + 32768 + w * 8192;
    const char* gA = (const char*)ehg;
    const char* gB = (const char*)elg;
#pragma unroll
    for (int r = 0; r < 8; ++r) {
      int o = w * 8192 + r * 1024 + lane * 16;
      int l = o ^ (((o >> 8) & 15) << 4);
      glds16(gA + l, ldsA + r * 1024);
      glds16(gB + l, ldsB + r * 1024);
    }
    glds16((const char*)eh2g + w * 1024 + lane * 16, smem + EH2_OFF + w * 1024);
  }

  // x B-fragments: fp32 global (64B-segment coalesced) -> bf16 hi/lo in regs
  bf16x8 xh[8], xl[8];
  {
    const float* xp = x + bOff + t;
    const int dbase = hf * 8;
#pragma unroll
    for (int ds = 0; ds < 8; ++ds) {
#pragma unroll
      for (int j = 0; j < 8; ++j) {
        float f = xp[(size_t)(ds * 16 + dbase + j) * 2048];
        unsigned short h = f2bf(f);
        float res = f - bf2f(h);
        xh[ds][j] = (short)h;
        xl[ds][j] = (short)f2bf(res);
      }
    }
  }

  __syncthreads();  // chunk 0 + eh2 ready (syncthreads drains vmcnt)

  float v1 = -FLT_MAX, v2 = -FLT_MAX;
  int k1 = 0, k2 = 0;

  for (int c = 0; c < 8; ++c) {
    const char* bufp = smem + (c & 1) * EBUF_HALF;
    if (c < 7) {  // prefetch next chunk into other buffer (m97 pattern)
      const int nb = (c + 1) & 1;
      char* ldsA = smem + nb * EBUF_HALF + w * 8192;
      char* ldsB = smem + nb * EBUF_HALF + 32768 + w * 8192;
      const char* gA = (const char*)ehg + (c + 1) * 32768;
      const char* gB = (const char*)elg + (c + 1) * 32768;
#pragma unroll
      for (int r = 0; r < 8; ++r) {
        int o = w * 8192 + r * 1024 + lane * 16;
        int l = o ^ (((o >> 8) & 15) << 4);
        glds16(gA + l, ldsA + r * 1024);
        glds16(gB + l, ldsB + r * 1024);
      }
    }
#pragma unroll
    for (int kf = 0; kf < 4; ++kf) {
      const int kb = c * 128 + kf * 32;
      // C-init: acc[reg] = -0.5*|e_k|^2, k = kb + (reg&3) + 8*(reg>>2) + 4*hf
      f32x16 acc;
#pragma unroll
      for (int q = 0; q < 4; ++q) {
        float4 v = *(const float4*)&eh2s[kb + 4 * hf + 8 * q];
        acc[4 * q + 0] = v.x; acc[4 * q + 1] = v.y;
        acc[4 * q + 2] = v.z; acc[4 * q + 3] = v.w;
      }
      const int rowC = kf * 32 + c32;          // A row within chunk
      const int base = rowC * 256 + hf * 16;
      const int swz = (rowC & 15) << 4;
#pragma unroll
      for (int ds = 0; ds < 8; ++ds) {
        const int off = (base + ds * 32) ^ swz;
        bf16x8 ea = *(const bf16x8*)(bufp + off);
        bf16x8 eb = *(const bf16x8*)(bufp + 32768 + off);
        acc = __builtin_amdgcn_mfma_f32_32x32x16_bf16(ea, xh[ds], acc, 0, 0, 0);
        acc = __builtin_amdgcn_mfma_f32_32x32x16_bf16(ea, xl[ds], acc, 0, 0, 0);
        acc = __builtin_amdgcn_mfma_f32_32x32x16_bf16(eb, xh[ds], acc, 0, 0, 0);
      }
      // running top-2 (maximize score; in-lane k ascending, strict > keeps
      // first occurrence = smaller k, matching np.argmin)
#pragma unroll
      for (int r = 0; r < 16; ++r) {
        float s = acc[r];
        int kk = kb + (r & 3) + 8 * (r >> 2) + 4 * hf;
        bool b1 = s > v1;
        bool b2 = s > v2;
        v2 = b1 ? v1 : (b2 ? s : v2);
        k2 = b1 ? k1 : (b2 ? kk : k2);
        v1 = b1 ? s : v1;
        k1 = b1 ? kk : k1;
      }
    }
    __syncthreads();
  }

  // merge the two lane-halves' top-2 (candidates for a point live in lane and lane^32)
  float u1 = __shfl_xor(v1, 32, 64); int j1 = __shfl_xor(k1, 32, 64);
  float u2 = __shfl_xor(v2, 32, 64); int j2 = __shfl_xor(k2, 32, 64);
  bool a = (u1 > v1) || (u1 == v1 && j1 < k1);
  int w1k = a ? j1 : k1;
  float lsv = a ? v1 : u1; int lsk = a ? k1 : j1;   // loser's best
  float wsv = a ? u2 : v2; int wsk = a ? j2 : k2;   // winner's second
  bool bb = (lsv > wsv) || (lsv == wsv && lsk < wsk);
  int w2k = bb ? lsk : wsk;

  // exact fp32 rescore of both candidates: d2 = sum_d (x-e)^2
  {
    const int kc = hf ? w2k : w1k;
    const float* xc = x + bOff + t;
    const float* er = emb + (size_t)kc * 128;
    float dsum = 0.f;
#pragma unroll 4
    for (int dd = 0; dd < 128; ++dd) {
      float xv = xc[(size_t)dd * 2048];
      float df = xv - er[dd];
      dsum = fmaf(df, df, dsum);
    }
    float other = __shfl_xor(dsum, 32, 64);
    float d2a = hf ? other : dsum;   // candidate w1k
    float d2b = hf ? dsum : other;   // candidate w2k
    bool first = (d2a < d2b) || (d2a == d2b && w1k < w2k);
    if (hf == 0) kfin[w * 32 + c32] = first ? w1k : w2k;
  }
  __syncthreads();

  // epilogue E1: gather emb fp32 rows into LDS (reuse ebuf), stride 132 floats
  {
    float* qt = (float*)smem;
    const int tl = tid >> 1, hh = tid & 1;
    const float* er = emb + (size_t)kfin[tl] * 128 + hh * 64;
    float* qr = qt + tl * 132 + hh * 64;
#pragma unroll
    for (int j = 0; j < 16; ++j)
      *(float4*)&qr[j * 4] = *(const float4*)&er[j * 4];
  }
  __syncthreads();

  // epilogue E2: coalesced store of quantized + loss partial
  float lsum = 0.f;
  {
    const float* qt = (const float*)smem;
    const float* xb = x + bOff + tblk;
    float* ob = out + bOff + tblk;
#pragma unroll 4
    for (int it = 0; it < 64; ++it) {
      int idx2 = it * 256 + tid;
      int dd = idx2 >> 7, tt = idx2 & 127;
      float q = qt[tt * 132 + dd];
      float xv = xb[(size_t)dd * 2048 + tt];
      float df = q - xv;
      lsum = fmaf(df, df, lsum);
      ob[(size_t)dd * 2048 + tt] = q;
    }
  }
#pragma unroll
  for (int off = 32; off; off >>= 1) lsum += __shfl_down(lsum, off, 64);
  if (lane == 0) wsum[w] = lsum;
  __syncthreads();
  if (tid == 0) partial[blk] = (wsum[0] + wsum[1]) + (wsum[2] + wsum[3]);
}

__global__ void vq_loss(const float* __restrict__ partial, float* __restrict__ out) {
  int lane = threadIdx.x;  // 64 threads
  float s = (partial[lane] + partial[lane + 64]) +
            (partial[lane + 128] + partial[lane + 192]);
#pragma unroll
  for (int off = 32; off; off >>= 1) s += __shfl_down(s, off, 64);
  if (lane == 0) out[4194304] = 1.25f * s / 4194304.0f;
}

extern "C" void kernel_launch(void* const* d_in, const int* in_sizes, int n_in,
                              void* d_out, int out_size, void* d_ws, size_t ws_size,
                              hipStream_t stream) {
  const float* x   = (const float*)d_in[0];   // [16,1,128,2048]
  const float* emb = (const float*)d_in[1];   // [1024,128]
  float* out = (float*)d_out;
  char* ws = (char*)d_ws;
  unsigned short* ehg = (unsigned short*)ws;              // 256 KB
  unsigned short* elg = (unsigned short*)(ws + 262144);   // 256 KB
  float* eh2g = (float*)(ws + 524288);                    // 4 KB
  float* partial = (float*)(ws + 528384);                 // 1 KB
  vq_prep<<<64, 256, 0, stream>>>(emb, ehg, elg, eh2g);
  vq_main<<<256, 256, 0, stream>>>(x, emb, ehg, elg, eh2g, out, partial);
  vq_loss<<<1, 64, 0, stream>>>(partial, out);
}